// Round 3
// baseline (93.181 us; speedup 1.0000x reference)
//
#include <hip/hip_runtime.h>
#include <math.h>

// Problem constants (match reference)
#define BATCH 8192
#define NQ    512
#define NL    5
#define GRID    2048
#define BSTRIDE (GRID / 2)        // 1024 — hardcoded so trip count is static
#define NITER   (BATCH / BSTRIDE) // 8

// Output layout (harness keeps REAL parts of the complex64 reference):
//   out[0 .. B*N*2)     : state reals, per (b,n): s0.re, s1.re
//   out[B*N*2 .. B*N*3) : O real = |s0|^2 - |s1|^2
//
// Math: per layer j, state <- Rz(rz_j) . Rx(x + rx_j) . state  (adjacent Rx
// rotations commute and merge). Angle addition splits sincos((x+rx_j)/2)
// into sincos(x/2) (1 per element) and sincos(rx_j/2) (hoisted per-qubit).
__global__ __launch_bounds__(256, 8) void qsim_kernel(
    const float* __restrict__ x,      // [BATCH][NQ]
    const float* __restrict__ fRx,    // [NL][NQ]
    const float* __restrict__ fRz,    // [NL][NQ]
    float* __restrict__ out)
{
    const int n  = (blockIdx.x & 1) * 256 + threadIdx.x;
    const int b0 = blockIdx.x >> 1;

    // ---- per-qubit, per-layer constants (hoisted; native trig only) ----
    float srx[NL], crx[NL];  // sincos(fRx[j][n]/2)
    float pzr[NL], pzi[NL];  // Rz phase e^{-i c/2} = (cos(c/2), -sin(c/2))
#pragma unroll
    for (int j = 0; j < NL; ++j) {
        const float a = fRx[j * NQ + n] * 0.5f;
        srx[j] = __sinf(a);
        crx[j] = __cosf(a);
        const float c = fRz[j * NQ + n] * 0.5f;
        pzr[j] = __cosf(c);
        pzi[j] = -__sinf(c);
    }

    float* __restrict__ stateOut = out;                          // B*N float2 (s0.re, s1.re)
    float* __restrict__ oOut     = out + (size_t)BATCH * NQ * 2; // B*N floats

    // Preload all 8 x values — 8 independent loads in flight per wave.
    float xv[NITER];
#pragma unroll
    for (int t = 0; t < NITER; ++t)
        xv[t] = x[(size_t)(b0 + t * BSTRIDE) * NQ + n];

#pragma unroll
    for (int t = 0; t < NITER; ++t) {
        const float h  = xv[t] * 0.5f;
        const float sx = __sinf(h);
        const float cx = __cosf(h);

        // |0> state
        float s0r = 1.f, s0i = 0.f, s1r = 0.f, s1i = 0.f;

#pragma unroll
        for (int j = 0; j < NL; ++j) {
            // sincos((x + rx_j)/2) via angle addition — no per-layer trans ops
            const float sa = sx * crx[j] + cx * srx[j];
            const float ca = cx * crx[j] - sx * srx[j];
            // Rx: [ca, -i sa; -i sa, ca]
            const float n0r =  ca * s0r + sa * s1i;
            const float n0i =  ca * s0i - sa * s1r;
            const float n1r =  sa * s0i + ca * s1r;
            const float n1i = -sa * s0r + ca * s1i;
            // Rz: s0 *= (pzr + i pzi); s1 *= conj(...)
            s0r = pzr[j] * n0r - pzi[j] * n0i;
            s0i = pzr[j] * n0i + pzi[j] * n0r;
            s1r = pzr[j] * n1r + pzi[j] * n1i;
            s1i = pzr[j] * n1i - pzi[j] * n1r;
        }

        const size_t idx = (size_t)(b0 + t * BSTRIDE) * NQ + n;
        *reinterpret_cast<float2*>(stateOut + idx * 2) = make_float2(s0r, s1r);
        oOut[idx] = (s0r * s0r + s0i * s0i) - (s1r * s1r + s1i * s1i);
    }
}

extern "C" void kernel_launch(void* const* d_in, const int* in_sizes, int n_in,
                              void* d_out, int out_size, void* d_ws, size_t ws_size,
                              hipStream_t stream) {
    const float* x   = (const float*)d_in[0];  // (B, N)
    const float* fRx = (const float*)d_in[1];  // (L, N)
    const float* fRz = (const float*)d_in[2];  // (L, N)
    float* out = (float*)d_out;

    qsim_kernel<<<dim3(GRID), dim3(256), 0, stream>>>(x, fRx, fRz, out);
}

// Round 4
// 92.970 us; speedup vs baseline: 1.0023x; 1.0023x over previous
//
#include <hip/hip_runtime.h>
#include <math.h>

// Problem constants (match reference)
#define BATCH 8192
#define NQ    512
#define NL    5
#define GRID  2048
#define NITER (BATCH / GRID)  // 4 b-rows per block

// Output layout (harness keeps REAL parts of the complex64 reference):
//   out[0 .. B*N*2)     : state reals, per (b,n): s0.re, s1.re
//   out[B*N*2 .. B*N*3) : O real = |s0|^2 - |s1|^2
//
// Mapping: lane owns qubits n2, n2+1 (n2 = 2*tid); block owns b-rows
// blockIdx.x + t*GRID, t in [0,4). Loads: float2; stores: float4 (state)
// + float2 (O) — 16B/8B per lane, fully coalesced.
//
// Math: per layer j, state <- Rz(rz_j) . Rx(x + rx_j) . state (same-axis Rx
// merge). sincos((x+rx_j)/2) via angle addition: one native sin+cos of x/2
// per element; per-qubit sincos hoisted to the preamble.
__global__ __launch_bounds__(256) void qsim_kernel(
    const float* __restrict__ x,      // [BATCH][NQ]
    const float* __restrict__ fRx,    // [NL][NQ]
    const float* __restrict__ fRz,    // [NL][NQ]
    float* __restrict__ out)
{
    const int n2 = threadIdx.x * 2;
    const int b0 = blockIdx.x;

    // ---- per-qubit, per-layer constants (hoisted; native trig only) ----
    float srx[NL][2], crx[NL][2];  // sincos(fRx[j][n]/2)
    float pzr[NL][2], pzi[NL][2];  // Rz phase e^{-i c/2} = (cos, -sin)
#pragma unroll
    for (int j = 0; j < NL; ++j) {
        const float2 ax = *reinterpret_cast<const float2*>(fRx + j * NQ + n2);
        const float2 az = *reinterpret_cast<const float2*>(fRz + j * NQ + n2);
        const float a0 = ax.x * 0.5f, a1 = ax.y * 0.5f;
        const float c0 = az.x * 0.5f, c1 = az.y * 0.5f;
        srx[j][0] = __sinf(a0);  crx[j][0] = __cosf(a0);
        srx[j][1] = __sinf(a1);  crx[j][1] = __cosf(a1);
        pzr[j][0] = __cosf(c0);  pzi[j][0] = -__sinf(c0);
        pzr[j][1] = __cosf(c1);  pzi[j][1] = -__sinf(c1);
    }

    float* __restrict__ stateOut = out;                          // B*N float2 (s0.re, s1.re)
    float* __restrict__ oOut     = out + (size_t)BATCH * NQ * 2; // B*N floats

    // Preload all 4 x float2s — independent loads in flight.
    float2 xv[NITER];
#pragma unroll
    for (int t = 0; t < NITER; ++t)
        xv[t] = *reinterpret_cast<const float2*>(x + (size_t)(b0 + t * GRID) * NQ + n2);

#pragma unroll
    for (int t = 0; t < NITER; ++t) {
        float st[4];  // s0r(n2), s1r(n2), s0r(n2+1), s1r(n2+1)
        float ov[2];

#pragma unroll
        for (int q = 0; q < 2; ++q) {
            const float h  = (q ? xv[t].y : xv[t].x) * 0.5f;
            const float sx = __sinf(h);
            const float cx = __cosf(h);

            float s0r = 1.f, s0i = 0.f, s1r = 0.f, s1i = 0.f;
#pragma unroll
            for (int j = 0; j < NL; ++j) {
                // sincos((x + rx_j)/2) via angle addition
                const float sa = sx * crx[j][q] + cx * srx[j][q];
                const float ca = cx * crx[j][q] - sx * srx[j][q];
                // Rx: [ca, -i sa; -i sa, ca]
                const float n0r =  ca * s0r + sa * s1i;
                const float n0i =  ca * s0i - sa * s1r;
                const float n1r =  sa * s0i + ca * s1r;
                const float n1i = -sa * s0r + ca * s1i;
                // Rz: s0 *= (pzr + i pzi); s1 *= conj(...)
                s0r = pzr[j][q] * n0r - pzi[j][q] * n0i;
                s0i = pzr[j][q] * n0i + pzi[j][q] * n0r;
                s1r = pzr[j][q] * n1r + pzi[j][q] * n1i;
                s1i = pzr[j][q] * n1i - pzi[j][q] * n1r;
            }
            st[q * 2 + 0] = s0r;
            st[q * 2 + 1] = s1r;
            ov[q] = (s0r * s0r + s0i * s0i) - (s1r * s1r + s1i * s1i);
        }

        const size_t idx = (size_t)(b0 + t * GRID) * NQ + n2;
        *reinterpret_cast<float4*>(stateOut + idx * 2) =
            make_float4(st[0], st[1], st[2], st[3]);
        *reinterpret_cast<float2*>(oOut + idx) = make_float2(ov[0], ov[1]);
    }
}

extern "C" void kernel_launch(void* const* d_in, const int* in_sizes, int n_in,
                              void* d_out, int out_size, void* d_ws, size_t ws_size,
                              hipStream_t stream) {
    const float* x   = (const float*)d_in[0];  // (B, N)
    const float* fRx = (const float*)d_in[1];  // (L, N)
    const float* fRz = (const float*)d_in[2];  // (L, N)
    float* out = (float*)d_out;

    qsim_kernel<<<dim3(GRID), dim3(256), 0, stream>>>(x, fRx, fRz, out);
}

// Round 8
// 88.253 us; speedup vs baseline: 1.0558x; 1.0534x over previous
//
#include <hip/hip_runtime.h>
#include <math.h>

// Problem constants (match reference)
#define BATCH 8192
#define NQ    512
#define NL    5
#define GRID  2048
#define NITER (BATCH / GRID)  // 4 b-rows per block

// Clang native vector types — required by __builtin_nontemporal_load/store
// (HIP_vector_type float2/float4 are classes and are rejected).
typedef float vfloat2 __attribute__((ext_vector_type(2)));
typedef float vfloat4 __attribute__((ext_vector_type(4)));

// Output layout (harness keeps REAL parts of the complex64 reference):
//   out[0 .. B*N*2)     : state reals, per (b,n): s0.re, s1.re
//   out[B*N*2 .. B*N*3) : O real = |s0|^2 - |s1|^2
//
// Mapping: lane owns qubits n2, n2+1 (n2 = 2*tid); block owns b-rows
// blockIdx.x + t*GRID, t in [0,4). Loads: vfloat2 (NT — read-once stream);
// stores: vfloat4 state + vfloat2 O (NT — write-once stream; out buffer is
// 48 MB > 32 MB aggregate L2, so bypassing write-allocate avoids L2 thrash).
//
// Math: per layer j, state <- Rz(rz_j) . Rx(x + rx_j) . state (same-axis Rx
// merge). sincos((x+rx_j)/2) via angle addition: one native sin+cos of x/2
// per element; per-qubit sincos hoisted to the preamble.
__global__ __launch_bounds__(256) void qsim_kernel(
    const float* __restrict__ x,      // [BATCH][NQ]
    const float* __restrict__ fRx,    // [NL][NQ]
    const float* __restrict__ fRz,    // [NL][NQ]
    float* __restrict__ out)
{
    const int n2 = threadIdx.x * 2;
    const int b0 = blockIdx.x;

    // ---- per-qubit, per-layer constants (hoisted; native trig only) ----
    float srx[NL][2], crx[NL][2];  // sincos(fRx[j][n]/2)
    float pzr[NL][2], pzi[NL][2];  // Rz phase e^{-i c/2} = (cos, -sin)
#pragma unroll
    for (int j = 0; j < NL; ++j) {
        const vfloat2 ax = *reinterpret_cast<const vfloat2*>(fRx + j * NQ + n2);
        const vfloat2 az = *reinterpret_cast<const vfloat2*>(fRz + j * NQ + n2);
        const float a0 = ax.x * 0.5f, a1 = ax.y * 0.5f;
        const float c0 = az.x * 0.5f, c1 = az.y * 0.5f;
        srx[j][0] = __sinf(a0);  crx[j][0] = __cosf(a0);
        srx[j][1] = __sinf(a1);  crx[j][1] = __cosf(a1);
        pzr[j][0] = __cosf(c0);  pzi[j][0] = -__sinf(c0);
        pzr[j][1] = __cosf(c1);  pzi[j][1] = -__sinf(c1);
    }

    float* __restrict__ stateOut = out;                          // B*N pairs (s0.re, s1.re)
    float* __restrict__ oOut     = out + (size_t)BATCH * NQ * 2; // B*N floats

    // Preload all 4 x vfloat2s — independent NT loads in flight.
    vfloat2 xv[NITER];
#pragma unroll
    for (int t = 0; t < NITER; ++t) {
        const vfloat2* p = reinterpret_cast<const vfloat2*>(
            x + (size_t)(b0 + t * GRID) * NQ + n2);
        xv[t] = __builtin_nontemporal_load(p);
    }

#pragma unroll
    for (int t = 0; t < NITER; ++t) {
        float st[4];  // s0r(n2), s1r(n2), s0r(n2+1), s1r(n2+1)
        float ov[2];

#pragma unroll
        for (int q = 0; q < 2; ++q) {
            const float h  = (q ? xv[t].y : xv[t].x) * 0.5f;
            const float sx = __sinf(h);
            const float cx = __cosf(h);

            float s0r = 1.f, s0i = 0.f, s1r = 0.f, s1i = 0.f;
#pragma unroll
            for (int j = 0; j < NL; ++j) {
                // sincos((x + rx_j)/2) via angle addition
                const float sa = sx * crx[j][q] + cx * srx[j][q];
                const float ca = cx * crx[j][q] - sx * srx[j][q];
                // Rx: [ca, -i sa; -i sa, ca]
                const float n0r =  ca * s0r + sa * s1i;
                const float n0i =  ca * s0i - sa * s1r;
                const float n1r =  sa * s0i + ca * s1r;
                const float n1i = -sa * s0r + ca * s1i;
                // Rz: s0 *= (pzr + i pzi); s1 *= conj(...)
                s0r = pzr[j][q] * n0r - pzi[j][q] * n0i;
                s0i = pzr[j][q] * n0i + pzi[j][q] * n0r;
                s1r = pzr[j][q] * n1r + pzi[j][q] * n1i;
                s1i = pzr[j][q] * n1i - pzi[j][q] * n1r;
            }
            st[q * 2 + 0] = s0r;
            st[q * 2 + 1] = s1r;
            ov[q] = (s0r * s0r + s0i * s0i) - (s1r * s1r + s1i * s1i);
        }

        const size_t idx = (size_t)(b0 + t * GRID) * NQ + n2;
        vfloat4 sv; sv.x = st[0]; sv.y = st[1]; sv.z = st[2]; sv.w = st[3];
        __builtin_nontemporal_store(
            sv, reinterpret_cast<vfloat4*>(stateOut + idx * 2));
        vfloat2 o2; o2.x = ov[0]; o2.y = ov[1];
        __builtin_nontemporal_store(
            o2, reinterpret_cast<vfloat2*>(oOut + idx));
    }
}

extern "C" void kernel_launch(void* const* d_in, const int* in_sizes, int n_in,
                              void* d_out, int out_size, void* d_ws, size_t ws_size,
                              hipStream_t stream) {
    const float* x   = (const float*)d_in[0];  // (B, N)
    const float* fRx = (const float*)d_in[1];  // (L, N)
    const float* fRz = (const float*)d_in[2];  // (L, N)
    float* out = (float*)d_out;

    qsim_kernel<<<dim3(GRID), dim3(256), 0, stream>>>(x, fRx, fRz, out);
}